// Round 11
// baseline (445.639 us; speedup 1.0000x reference)
//
#include <hip/hip_runtime.h>
#include <hip/hip_fp16.h>

#define L_SEQ  1024
#define NBATCH 2048
#define NSTATE 64
#define TCHK   64
#define NCHK   16    // L_SEQ / TCHK
#define KDIM   128   // NSTATE + TCHK

typedef _Float16 half8  __attribute__((ext_vector_type(8)));
typedef _Float16 half2s __attribute__((ext_vector_type(2)));
typedef float    float4v __attribute__((ext_vector_type(4)));
typedef unsigned int uint2v __attribute__((ext_vector_type(2)));
typedef unsigned int uint4v __attribute__((ext_vector_type(4)));

// ---------------------------------------------------------------------------
__global__ __launch_bounds__(256) void split_A_kernel(const float* __restrict__ A,
                                                      _Float16* __restrict__ hi,
                                                      _Float16* __restrict__ lo) {
    int i = blockIdx.x * 256 + threadIdx.x;
    float a = A[i];
    _Float16 h = (_Float16)a;
    hi[i] = h;
    lo[i] = (_Float16)(a - (float)h);
}

// ---------------------------------------------------------------------------
// Kernel 1 v5: build G — grid = (chunk, col-tile) = 128 one-wave blocks
// (R9 form, which the R10 A/B showed is as fast as the 4-wave variant).
// NEW: inactive col-tiles (ct*16 > lim) store G's zero tail directly, so the
// separate zero_G kernel + graph node is gone. Active tiles already produce
// correct zeros for columns > lim (their LDS state is zero throughout).
__global__ __launch_bounds__(64, 1) void build_G_kernel(
    const _Float16* __restrict__ Ahi,   // (L, 64, 64)
    const _Float16* __restrict__ Alo,
    const float* __restrict__ bst,      // (L, 64)
    _Float16* __restrict__ Ghi,         // (NCHK, 64*64, 128) row-major
    _Float16* __restrict__ Glo)
{
    const int lane = threadIdx.x;
    const int col  = lane & 15;
    const int quad = lane >> 4;
    const int chunk = blockIdx.x >> 3;
    const int ct    = blockIdx.x & 7;   // col-tile 0..7 (cols ct*16..ct*16+15)
    const int swz  = (col & 7) << 2;

    __shared__ unsigned int u_hi[1024];   // 2 buf x 16 rows(local col) x 32 u32
    __shared__ unsigned int u_lo[1024];
    for (int i = lane; i < 1024; i += 64) { u_hi[i] = 0u; u_lo[i] = 0u; }
    // identity into buf0 (state cols only): U_{-1}[j, c] = delta_{j,c}
    if (ct < 4 && lane < 16) {
        int c = ct * 16 + lane;          // global col, < 64
        u_hi[lane * 32 + (((c >> 1) & 31) ^ ((lane & 7) << 2))] =
            (c & 1) ? 0x3C000000u : 0x00003C00u;
    }

    int aoff[4][2];
#pragma unroll
    for (int tl = 0; tl < 4; ++tl)
#pragma unroll
        for (int kk = 0; kk < 2; ++kk)
            aoff[tl][kk] = (16 * tl + col) * 64 + 32 * kk + 8 * quad;

    half8 aH0[4][2], aL0[4][2], aH1[4][2], aL1[4][2];
    float4v bs0[4], bs1[4];

    auto loadA = [&](int i, half8 (&aH)[4][2], half8 (&aL)[4][2], float4v (&bs)[4]) {
        size_t base = (size_t)(chunk * TCHK + i) * 4096;
#pragma unroll
        for (int tl = 0; tl < 4; ++tl) {
#pragma unroll
            for (int kk = 0; kk < 2; ++kk) {
                aH[tl][kk] = *(const half8*)(Ahi + base + aoff[tl][kk]);
                aL[tl][kk] = *(const half8*)(Alo + base + aoff[tl][kk]);
            }
            bs[tl] = *(const float4v*)(bst + (chunk * TCHK + i) * NSTATE + 16 * tl + 4 * quad);
        }
    };

    loadA(0, aH0, aL0, bs0);
    loadA(1, aH1, aL1, bs1);

    const float4v zero4 = {0.0f, 0.0f, 0.0f, 0.0f};

    auto stepG = [&](int i, half8 (&aH)[4][2], half8 (&aL)[4][2], float4v (&bs)[4]) {
        const int cur = (i & 1) << 9;        // *512 (16 rows x 32 u32)
        const int nxt = cur ^ 512;
        const int lim = 64 + i;              // highest active column
        const int inj_ct = lim >> 4, inj_c = lim & 15;

        if (ct * 16 <= lim) {
            int rowb = cur + col * 32;
            uint4v uh0 = *(const uint4v*)(u_hi + rowb + (( 0 + 4 * quad) ^ swz));
            uint4v uh1 = *(const uint4v*)(u_hi + rowb + ((16 + 4 * quad) ^ swz));
            uint4v ul0 = *(const uint4v*)(u_lo + rowb + (( 0 + 4 * quad) ^ swz));
            uint4v ul1 = *(const uint4v*)(u_lo + rowb + ((16 + 4 * quad) ^ swz));
            half8 ch0 = __builtin_bit_cast(half8, uh0), ch1 = __builtin_bit_cast(half8, uh1);
            half8 cl0 = __builtin_bit_cast(half8, ul0), cl1 = __builtin_bit_cast(half8, ul1);

#pragma unroll
            for (int tl = 0; tl < 4; ++tl) {
                float4v a = zero4;
                a = __builtin_amdgcn_mfma_f32_16x16x32_f16(aH[tl][0], ch0, a, 0, 0, 0);
                a = __builtin_amdgcn_mfma_f32_16x16x32_f16(aH[tl][1], ch1, a, 0, 0, 0);
                a = __builtin_amdgcn_mfma_f32_16x16x32_f16(aH[tl][0], cl0, a, 0, 0, 0);
                a = __builtin_amdgcn_mfma_f32_16x16x32_f16(aH[tl][1], cl1, a, 0, 0, 0);
                a = __builtin_amdgcn_mfma_f32_16x16x32_f16(aL[tl][0], ch0, a, 0, 0, 0);
                a = __builtin_amdgcn_mfma_f32_16x16x32_f16(aL[tl][1], ch1, a, 0, 0, 0);
                if (ct == inj_ct && col == inj_c) a += bs[tl];

                _Float16 hx = (_Float16)a.x, hy = (_Float16)a.y;
                _Float16 hz = (_Float16)a.z, hw = (_Float16)a.w;
                _Float16 lx = (_Float16)(a.x - (float)hx), ly = (_Float16)(a.y - (float)hy);
                _Float16 lz = (_Float16)(a.z - (float)hz), lw = (_Float16)(a.w - (float)hw);
                half2s hp01; hp01.x = hx; hp01.y = hy;
                half2s hp23; hp23.x = hz; hp23.y = hw;
                half2s lp01; lp01.x = lx; lp01.y = ly;
                half2s lp23; lp23.x = lz; lp23.y = lw;
                uint2v hp = { __builtin_bit_cast(unsigned int, hp01), __builtin_bit_cast(unsigned int, hp23) };
                uint2v lp = { __builtin_bit_cast(unsigned int, lp01), __builtin_bit_cast(unsigned int, lp23) };
                *(uint2v*)(u_hi + nxt + col * 32 + ((8 * tl + 2 * quad) ^ swz)) = hp;
                *(uint2v*)(u_lo + nxt + col * 32 + ((8 * tl + 2 * quad) ^ swz)) = lp;

                size_t grow = ((size_t)(chunk * TCHK + i) * NSTATE + 16 * tl + 4 * quad) * KDIM + ct * 16 + col;
                Ghi[grow          ] = hx; Glo[grow          ] = lx;
                Ghi[grow +     KDIM] = hy; Glo[grow +     KDIM] = ly;
                Ghi[grow + 2 * KDIM] = hz; Glo[grow + 2 * KDIM] = lz;
                Ghi[grow + 3 * KDIM] = hw; Glo[grow + 3 * KDIM] = lw;
            }
        } else {
            // inactive col-tile: write G's zero tail (replaces zero_G kernel)
            const _Float16 z = (_Float16)0.0f;
#pragma unroll
            for (int tl = 0; tl < 4; ++tl) {
                size_t grow = ((size_t)(chunk * TCHK + i) * NSTATE + 16 * tl + 4 * quad) * KDIM + ct * 16 + col;
                Ghi[grow          ] = z; Glo[grow          ] = z;
                Ghi[grow +     KDIM] = z; Glo[grow +     KDIM] = z;
                Ghi[grow + 2 * KDIM] = z; Glo[grow + 2 * KDIM] = z;
                Ghi[grow + 3 * KDIM] = z; Glo[grow + 3 * KDIM] = z;
            }
        }
        int tp = i + 2; if (tp > TCHK - 1) tp = TCHK - 1;
        loadA(tp, aH, aL, bs);
    };

    for (int i = 0; i < TCHK; i += 2) {
        stepG(i,     aH0, aL0, bs0);
        stepG(i + 1, aH1, aL1, bs1);
    }
}

// ---------------------------------------------------------------------------
// Kernel 2 v2: boundary scan, pipelined. Unchanged (verified).
__global__ __launch_bounds__(256, 1) void boundary2_kernel(
    const float* __restrict__ inp,      // (L, NBATCH)
    const _Float16* __restrict__ Ghi,
    const _Float16* __restrict__ Glo,
    unsigned int* __restrict__ s_hi,    // (NCHK, NBATCH, 32)
    unsigned int* __restrict__ s_lo)
{
    const int tid  = threadIdx.x;
    const int lane = tid & 63;
    const int wave = tid >> 6;
    const int col  = lane & 15;
    const int quad = lane >> 4;
    const int b0   = blockIdx.x * 64;
    const int b    = b0 + wave * 16 + col;
    const int swz  = (col & 7) << 2;

    __shared__ _Float16 gstage[2][2][64][128];   // [buf][hi/lo][row][c] = 64 KB
    __shared__ float    istage[2][64][64];       // [buf][t][b-local]    = 32 KB
    __shared__ unsigned int cst[4][2][512];      // [wave][hi/lo][16 b x 32 u32] = 16 KB

    for (int i = lane; i < 512; i += 64) { cst[wave][0][i] = 0u; cst[wave][1][i] = 0u; }
    {
        const uint4v z4 = {0u, 0u, 0u, 0u};
        size_t sb = ((size_t)b) * 32 + 8 * quad;
        *(uint4v*)(s_hi + sb) = z4; *(uint4v*)(s_hi + sb + 4) = z4;
        *(uint4v*)(s_lo + sb) = z4; *(uint4v*)(s_lo + sb + 4) = z4;
    }

    half8  gr[8];
    float4v ir[4];
    auto stage_issue = [&](int k) {
        size_t base = (size_t)(k * TCHK + 63) * NSTATE * KDIM;
#pragma unroll
        for (int j = 0; j < 8; ++j) {
            int off = j * 2048 + tid * 8;
            gr[j] = (off < 8192) ? *(const half8*)(Ghi + base + off)
                                 : *(const half8*)(Glo + base + off - 8192);
        }
#pragma unroll
        for (int q2 = 0; q2 < 4; ++q2) {
            int fi   = q2 * 256 + tid;
            int tloc = fi >> 4;
            int f4   = fi & 15;
            ir[q2] = *(const float4v*)(inp + (size_t)(k * TCHK + tloc) * NBATCH + b0 + f4 * 4);
        }
    };
    auto stage_write = [&](int buf) {
#pragma unroll
        for (int j = 0; j < 8; ++j) {
            int off = j * 2048 + tid * 8;
            int reg = off >> 13;
            int loff = off & 8191;
            int row = loff >> 7;
            int c   = (loff & 127) ^ ((row & 7) << 3);
            *(half8*)&gstage[buf][reg][row][c] = gr[j];
        }
#pragma unroll
        for (int q2 = 0; q2 < 4; ++q2) {
            int fi   = q2 * 256 + tid;
            int tloc = fi >> 4;
            int f4   = fi & 15;
            *(float4v*)&istage[buf][tloc][f4 * 4] = ir[q2];
        }
    };

    const float4v zero4 = {0.0f, 0.0f, 0.0f, 0.0f};

    stage_issue(0);
    stage_write(0);
    __syncthreads();

    for (int k = 0; k < NCHK; ++k) {
        const int cur = k & 1;
        if (k < NCHK - 1) stage_issue(k + 1);

        uint4v uh0 = *(const uint4v*)(cst[wave][0] + col * 32 + (( 0 + 4 * quad) ^ swz));
        uint4v uh1 = *(const uint4v*)(cst[wave][0] + col * 32 + ((16 + 4 * quad) ^ swz));
        uint4v ul0 = *(const uint4v*)(cst[wave][1] + col * 32 + (( 0 + 4 * quad) ^ swz));
        uint4v ul1 = *(const uint4v*)(cst[wave][1] + col * 32 + ((16 + 4 * quad) ^ swz));
        half8 xh[4], xl[4];
        xh[0] = __builtin_bit_cast(half8, uh0); xh[1] = __builtin_bit_cast(half8, uh1);
        xl[0] = __builtin_bit_cast(half8, ul0); xl[1] = __builtin_bit_cast(half8, ul1);
#pragma unroll
        for (int kk2 = 0; kk2 < 2; ++kk2) {
            half8 h, l;
#pragma unroll
            for (int e = 0; e < 8; ++e) {
                float v = istage[cur][kk2 * 32 + 8 * quad + e][wave * 16 + col];
                _Float16 hh = (_Float16)v;
                h[e] = hh; l[e] = (_Float16)(v - (float)hh);
            }
            xh[2 + kk2] = h; xl[2 + kk2] = l;
        }

        float4v acc[4];
#pragma unroll
        for (int tl = 0; tl < 4; ++tl) {
            float4v a = zero4;
#pragma unroll
            for (int kk = 0; kk < 4; ++kk) {
                const int row = 16 * tl + col;
                const int c   = (32 * kk + 8 * quad) ^ ((col & 7) << 3);
                half8 gh = *(const half8*)&gstage[cur][0][row][c];
                half8 gl = *(const half8*)&gstage[cur][1][row][c];
                a = __builtin_amdgcn_mfma_f32_16x16x32_f16(gh, xh[kk], a, 0, 0, 0);
                a = __builtin_amdgcn_mfma_f32_16x16x32_f16(gh, xl[kk], a, 0, 0, 0);
                a = __builtin_amdgcn_mfma_f32_16x16x32_f16(gl, xh[kk], a, 0, 0, 0);
            }
            acc[tl] = a;
        }

        if (k < NCHK - 1) {
#pragma unroll
            for (int tl = 0; tl < 4; ++tl) {
                float4v a = acc[tl];
                _Float16 hx = (_Float16)a.x, hy = (_Float16)a.y;
                _Float16 hz = (_Float16)a.z, hw = (_Float16)a.w;
                _Float16 lx = (_Float16)(a.x - (float)hx), ly = (_Float16)(a.y - (float)hy);
                _Float16 lz = (_Float16)(a.z - (float)hz), lw = (_Float16)(a.w - (float)hw);
                half2s hp01; hp01.x = hx; hp01.y = hy;
                half2s hp23; hp23.x = hz; hp23.y = hw;
                half2s lp01; lp01.x = lx; lp01.y = ly;
                half2s lp23; lp23.x = lz; lp23.y = lw;
                uint2v hp = { __builtin_bit_cast(unsigned int, hp01), __builtin_bit_cast(unsigned int, hp23) };
                uint2v lp = { __builtin_bit_cast(unsigned int, lp01), __builtin_bit_cast(unsigned int, lp23) };
                *(uint2v*)(cst[wave][0] + col * 32 + ((8 * tl + 2 * quad) ^ swz)) = hp;
                *(uint2v*)(cst[wave][1] + col * 32 + ((8 * tl + 2 * quad) ^ swz)) = lp;
                size_t sb = ((size_t)(k + 1) * NBATCH + b) * 32 + 8 * tl + 2 * quad;
                *(uint2v*)(s_hi + sb) = hp;
                *(uint2v*)(s_lo + sb) = lp;
            }
            stage_write(cur ^ 1);
        }
        __syncthreads();
    }
}

// ---------------------------------------------------------------------------
// Kernel 3 v2: pipelined apply, plain stores. Unchanged (verified).
// THIS ROUND: launched TWICE (idempotent) — the timed delta vs R10 measures
// apply2's true duration, which rocprof cannot resolve.
__global__ __launch_bounds__(256, 1) void apply2_kernel(
    const float* __restrict__ inp,
    const _Float16* __restrict__ Ghi,
    const _Float16* __restrict__ Glo,
    const unsigned int* __restrict__ s_hi,
    const unsigned int* __restrict__ s_lo,
    float* __restrict__ out)
{
    const int tid  = threadIdx.x;
    const int lane = tid & 63;
    const int wave = tid >> 6;
    const int col  = lane & 15;
    const int quad = lane >> 4;

    const int virt  = (blockIdx.x & 7) * 256 + (blockIdx.x >> 3);
    const int chunk = virt >> 7;
    const int ig    = (virt >> 4) & 7;
    const int bt    = virt & 15;

    __shared__ _Float16 gbuf[2][2][16][64][8];

    int bb[2];
    bb[0] = bt * 128 + wave * 32 + col;
    bb[1] = bb[0] + 16;
    half8 xh[2][4], xl[2][4];
#pragma unroll
    for (int bs = 0; bs < 2; ++bs) {
        size_t sb = ((size_t)chunk * NBATCH + bb[bs]) * 32;
        uint4v sh0 = *(const uint4v*)(s_hi + sb +  0 + 4 * quad);
        uint4v sh1 = *(const uint4v*)(s_hi + sb + 16 + 4 * quad);
        uint4v sl0 = *(const uint4v*)(s_lo + sb +  0 + 4 * quad);
        uint4v sl1 = *(const uint4v*)(s_lo + sb + 16 + 4 * quad);
        xh[bs][0] = __builtin_bit_cast(half8, sh0); xh[bs][1] = __builtin_bit_cast(half8, sh1);
        xl[bs][0] = __builtin_bit_cast(half8, sl0); xl[bs][1] = __builtin_bit_cast(half8, sl1);
#pragma unroll
        for (int kk2 = 0; kk2 < 2; ++kk2) {
            half8 h, l;
#pragma unroll
            for (int e = 0; e < 8; ++e) {
                float v = inp[(size_t)(chunk * TCHK + kk2 * 32 + 8 * quad + e) * NBATCH + bb[bs]];
                _Float16 hh = (_Float16)v;
                h[e] = hh; l[e] = (_Float16)(v - (float)hh);
            }
            xh[bs][2 + kk2] = h; xl[bs][2 + kk2] = l;
        }
    }

    half8 sreg[8];
    auto stage_issue = [&](int i) {
        size_t base = ((size_t)(chunk * TCHK + ig * 8 + i) * NSTATE + 16 * wave + col) * KDIM + 8 * quad;
#pragma unroll
        for (int kk = 0; kk < 4; ++kk) {
            sreg[kk * 2 + 0] = *(const half8*)(Ghi + base + 32 * kk);
            sreg[kk * 2 + 1] = *(const half8*)(Glo + base + 32 * kk);
        }
    };
    auto stage_write = [&](int buf) {
#pragma unroll
        for (int kk = 0; kk < 4; ++kk) {
            *(half8*)&gbuf[buf][0][wave * 4 + kk][lane][0] = sreg[kk * 2 + 0];
            *(half8*)&gbuf[buf][1][wave * 4 + kk][lane][0] = sreg[kk * 2 + 1];
        }
    };

    const float4v zero4 = {0.0f, 0.0f, 0.0f, 0.0f};
    float4v* outv = (float4v*)out;

    stage_issue(0);
    stage_write(0);
    __syncthreads();

    for (int i = 0; i < 8; ++i) {
        const int cur = i & 1;
        if (i < 7) stage_issue(i + 1);

        float4v acc[2][4];
#pragma unroll
        for (int bs = 0; bs < 2; ++bs)
#pragma unroll
            for (int tl = 0; tl < 4; ++tl) acc[bs][tl] = zero4;

#pragma unroll
        for (int kk = 0; kk < 4; ++kk) {
            half8 gh[4], gl[4];
#pragma unroll
            for (int tl = 0; tl < 4; ++tl) {
                gh[tl] = *(const half8*)&gbuf[cur][0][tl * 4 + kk][lane][0];
                gl[tl] = *(const half8*)&gbuf[cur][1][tl * 4 + kk][lane][0];
            }
#pragma unroll
            for (int tl = 0; tl < 4; ++tl) {
#pragma unroll
                for (int bs = 0; bs < 2; ++bs) {
                    acc[bs][tl] = __builtin_amdgcn_mfma_f32_16x16x32_f16(gh[tl], xh[bs][kk], acc[bs][tl], 0, 0, 0);
                    acc[bs][tl] = __builtin_amdgcn_mfma_f32_16x16x32_f16(gh[tl], xl[bs][kk], acc[bs][tl], 0, 0, 0);
                    acc[bs][tl] = __builtin_amdgcn_mfma_f32_16x16x32_f16(gl[tl], xh[bs][kk], acc[bs][tl], 0, 0, 0);
                }
            }
        }

        const size_t tt = (size_t)(chunk * TCHK + ig * 8 + i);
#pragma unroll
        for (int bs = 0; bs < 2; ++bs)
#pragma unroll
            for (int tl = 0; tl < 4; ++tl)
                outv[(tt * NBATCH + bb[bs]) * 16 + 4 * tl + quad] = acc[bs][tl];

        if (i < 7) stage_write(cur ^ 1);
        __syncthreads();
    }
}

// ---------------------------------------------------------------------------
// R3 fallback: sequential per-step scan (verified passing).
template <bool USE_WS>
__global__ __launch_bounds__(64, 1) void hippo_scan_kernel(
    const float* __restrict__ inp, const float* __restrict__ bst,
    const float* __restrict__ A32, const _Float16* __restrict__ Ahi,
    const _Float16* __restrict__ Alo, float* __restrict__ out)
{
    const int lane = threadIdx.x;
    const int col  = lane & 15;
    const int quad = lane >> 4;
    const int b0   = blockIdx.x * 16;
    const int swz  = (col & 7) << 2;

    __shared__ unsigned int c_hi[1024];
    __shared__ unsigned int c_lo[1024];
    for (int i = lane; i < 1024; i += 64) { c_hi[i] = 0u; c_lo[i] = 0u; }

    const int rd0 = col * 32 + (( 0 + 4 * quad) ^ swz);
    const int rd1 = col * 32 + ((16 + 4 * quad) ^ swz);
    int wr[4];
#pragma unroll
    for (int ts = 0; ts < 4; ++ts) wr[ts] = col * 32 + ((8 * ts + 2 * quad) ^ swz);

    int aoff[4][2];
#pragma unroll
    for (int tl = 0; tl < 4; ++tl)
#pragma unroll
        for (int kk = 0; kk < 2; ++kk)
            aoff[tl][kk] = (16 * tl + col) * 64 + 32 * kk + 8 * quad;

    half8 ah0[4][2], al0[4][2], ah1[4][2], al1[4][2];
    float inp0, inp1;
    float4v bst0[4], bst1[4];

    auto load_set = [&](int t, half8 (&ah)[4][2], half8 (&al)[4][2],
                        float4v (&bstv)[4], float& inpv) {
#pragma unroll
        for (int tl = 0; tl < 4; ++tl) {
#pragma unroll
            for (int kk = 0; kk < 2; ++kk) {
                if constexpr (USE_WS) {
                    ah[tl][kk] = *(const half8*)(Ahi + (size_t)t * 4096 + aoff[tl][kk]);
                    al[tl][kk] = *(const half8*)(Alo + (size_t)t * 4096 + aoff[tl][kk]);
                } else {
                    const float* p = A32 + (size_t)t * 4096 + aoff[tl][kk];
                    float4v f0 = *(const float4v*)(p);
                    float4v f1 = *(const float4v*)(p + 4);
                    half8 h, l;
#pragma unroll
                    for (int e = 0; e < 4; ++e) {
                        float v0 = f0[e], v1 = f1[e];
                        _Float16 h0 = (_Float16)v0, h1 = (_Float16)v1;
                        h[e] = h0; h[e + 4] = h1;
                        l[e] = (_Float16)(v0 - (float)h0);
                        l[e + 4] = (_Float16)(v1 - (float)h1);
                    }
                    ah[tl][kk] = h; al[tl][kk] = l;
                }
            }
        }
        inpv = inp[t * NBATCH + b0 + col];
#pragma unroll
        for (int tl = 0; tl < 4; ++tl)
            bstv[tl] = *(const float4v*)(bst + t * NSTATE + 16 * tl + 4 * quad);
    };

    load_set(0, ah0, al0, bst0, inp0);
    load_set(1, ah1, al1, bst1, inp1);
    const float4v zero4 = {0.0f, 0.0f, 0.0f, 0.0f};

    auto step = [&](int t, int cur, half8 (&ah)[4][2], half8 (&al)[4][2],
                    float4v (&bstv)[4], float& inpv) {
        const int nxt = cur ^ 512;
        uint4v u_h0 = *(const uint4v*)(c_hi + cur + rd0);
        uint4v u_h1 = *(const uint4v*)(c_hi + cur + rd1);
        uint4v u_l0 = *(const uint4v*)(c_lo + cur + rd0);
        uint4v u_l1 = *(const uint4v*)(c_lo + cur + rd1);
        half8 ch[2] = { __builtin_bit_cast(half8, u_h0), __builtin_bit_cast(half8, u_h1) };
        half8 cl[2] = { __builtin_bit_cast(half8, u_l0), __builtin_bit_cast(half8, u_l1) };

        float4v acc[4];
#pragma unroll
        for (int tl = 0; tl < 4; ++tl) {
            float4v accA = bstv[tl] * inpv;
            accA = __builtin_amdgcn_mfma_f32_16x16x32_f16(ah[tl][0], ch[0], accA, 0, 0, 0);
            accA = __builtin_amdgcn_mfma_f32_16x16x32_f16(ah[tl][1], ch[1], accA, 0, 0, 0);
            float4v accB = __builtin_amdgcn_mfma_f32_16x16x32_f16(ah[tl][0], cl[0], zero4, 0, 0, 0);
            accB = __builtin_amdgcn_mfma_f32_16x16x32_f16(ah[tl][1], cl[1], accB, 0, 0, 0);
            accB = __builtin_amdgcn_mfma_f32_16x16x32_f16(al[tl][0], ch[0], accB, 0, 0, 0);
            accB = __builtin_amdgcn_mfma_f32_16x16x32_f16(al[tl][1], ch[1], accB, 0, 0, 0);
            acc[tl] = accA + accB;
        }

        float4v* outv = (float4v*)out;
#pragma unroll
        for (int tl = 0; tl < 4; ++tl)
            outv[(size_t)(t * NBATCH + b0 + col) * 16 + 4 * tl + quad] = acc[tl];

        int tp = t + 2; if (tp > L_SEQ - 1) tp = L_SEQ - 1;
        load_set(tp, ah, al, bstv, inpv);

#pragma unroll
        for (int tl = 0; tl < 4; ++tl) {
            float x = acc[tl].x, y = acc[tl].y, z = acc[tl].z, w = acc[tl].w;
            _Float16 hx = (_Float16)x, hy = (_Float16)y, hz = (_Float16)z, hw = (_Float16)w;
            half2s hp01; hp01.x = hx; hp01.y = hy;
            half2s hp23; hp23.x = hz; hp23.y = hw;
            half2s lp01; lp01.x = (_Float16)(x - (float)hx); lp01.y = (_Float16)(y - (float)hy);
            half2s lp23; lp23.x = (_Float16)(z - (float)hz); lp23.y = (_Float16)(w - (float)hw);
            uint2v hp = { __builtin_bit_cast(unsigned int, hp01), __builtin_bit_cast(unsigned int, hp23) };
            uint2v lp = { __builtin_bit_cast(unsigned int, lp01), __builtin_bit_cast(unsigned int, lp23) };
            *(uint2v*)(c_hi + nxt + wr[tl]) = hp;
            *(uint2v*)(c_lo + nxt + wr[tl]) = lp;
        }
    };

    for (int t = 0; t < L_SEQ; t += 2) {
        step(t,     0,   ah0, al0, bst0, inp0);
        step(t + 1, 512, ah1, al1, bst1, inp1);
    }
}

// ---------------------------------------------------------------------------
extern "C" void kernel_launch(void* const* d_in, const int* in_sizes, int n_in,
                              void* d_out, int out_size, void* d_ws, size_t ws_size,
                              hipStream_t stream) {
    const float* inputs = (const float*)d_in[0];
    const float* A_st   = (const float*)d_in[1];
    const float* B_st   = (const float*)d_in[2];
    float* out = (float*)d_out;

    const size_t n_a    = (size_t)L_SEQ * NSTATE * NSTATE;
    const size_t SZ_A   = n_a * sizeof(_Float16);                                 // 8 MB
    const size_t SZ_G   = (size_t)NCHK * TCHK * NSTATE * KDIM * sizeof(_Float16); // 16 MB
    const size_t SZ_S   = (size_t)NCHK * NBATCH * 32 * sizeof(unsigned int);      // 4 MB
    const size_t OFF_ALO = SZ_A;
    const size_t OFF_GHI = 2 * SZ_A;
    const size_t OFF_GLO = OFF_GHI + SZ_G;
    const size_t OFF_SHI = OFF_GLO + SZ_G;
    const size_t OFF_SLO = OFF_SHI + SZ_S;
    const size_t NEED    = OFF_SLO + SZ_S;                                        // 56 MB

    if (ws_size >= NEED) {
        char* ws = (char*)d_ws;
        _Float16* Ahi = (_Float16*)ws;
        _Float16* Alo = (_Float16*)(ws + OFF_ALO);
        _Float16* Ghi = (_Float16*)(ws + OFF_GHI);
        _Float16* Glo = (_Float16*)(ws + OFF_GLO);
        unsigned int* shi = (unsigned int*)(ws + OFF_SHI);
        unsigned int* slo = (unsigned int*)(ws + OFF_SLO);

        split_A_kernel<<<(int)(n_a / 256), 256, 0, stream>>>(A_st, Ahi, Alo);
        build_G_kernel<<<NCHK * 8, 64, 0, stream>>>(Ahi, Alo, B_st, Ghi, Glo);
        boundary2_kernel<<<NBATCH / 64, 256, 0, stream>>>(inputs, Ghi, Glo, shi, slo);
        // apply2 launched TWICE (idempotent): timed delta vs R10 = apply2's
        // true duration. Second launch rewrites identical output.
        apply2_kernel<<<NCHK * 8 * 16, 256, 0, stream>>>(inputs, Ghi, Glo, shi, slo, out);
        apply2_kernel<<<NCHK * 8 * 16, 256, 0, stream>>>(inputs, Ghi, Glo, shi, slo, out);
    } else if (ws_size >= 2 * SZ_A) {
        _Float16* Ahi = (_Float16*)d_ws;
        _Float16* Alo = Ahi + n_a;
        split_A_kernel<<<(int)(n_a / 256), 256, 0, stream>>>(A_st, Ahi, Alo);
        hippo_scan_kernel<true><<<NBATCH / 16, 64, 0, stream>>>(inputs, B_st, A_st, Ahi, Alo, out);
    } else {
        hippo_scan_kernel<false><<<NBATCH / 16, 64, 0, stream>>>(inputs, B_st, A_st, nullptr, nullptr, out);
    }
}

// Round 12
// 220.790 us; speedup vs baseline: 2.0184x; 2.0184x over previous
//
#include <hip/hip_runtime.h>
#include <hip/hip_fp16.h>

#define L_SEQ  1024
#define NBATCH 2048
#define NSTATE 64
#define TCHK   64
#define NCHK   16    // L_SEQ / TCHK
#define KDIM   128   // NSTATE + TCHK

typedef _Float16 half8  __attribute__((ext_vector_type(8)));
typedef _Float16 half2s __attribute__((ext_vector_type(2)));
typedef float    float4v __attribute__((ext_vector_type(4)));
typedef unsigned int uint2v __attribute__((ext_vector_type(2)));
typedef unsigned int uint4v __attribute__((ext_vector_type(4)));

// ---------------------------------------------------------------------------
__global__ __launch_bounds__(256) void split_A_kernel(const float* __restrict__ A,
                                                      _Float16* __restrict__ hi,
                                                      _Float16* __restrict__ lo) {
    int i = blockIdx.x * 256 + threadIdx.x;
    float a = A[i];
    _Float16 h = (_Float16)a;
    hi[i] = h;
    lo[i] = (_Float16)(a - (float)h);
}

// ---------------------------------------------------------------------------
// Kernel 1 v6: build G — 128 one-wave blocks (chunk, col-tile), fused zero
// tail. NEW: Glo is stored ONLY for i = 63 (the last rowblock): boundary
// reads Glo solely there, and apply (now 2-term) no longer reads Glo at all.
// Halves the scattered G-store volume. At i=63 every col-tile is active
// (lim=127), so the tail branch never needs Glo zeros.
__global__ __launch_bounds__(64, 1) void build_G_kernel(
    const _Float16* __restrict__ Ahi,   // (L, 64, 64)
    const _Float16* __restrict__ Alo,
    const float* __restrict__ bst,      // (L, 64)
    _Float16* __restrict__ Ghi,         // (NCHK, 64*64, 128) row-major
    _Float16* __restrict__ Glo)         // only rowblock i=63 per chunk is valid
{
    const int lane = threadIdx.x;
    const int col  = lane & 15;
    const int quad = lane >> 4;
    const int chunk = blockIdx.x >> 3;
    const int ct    = blockIdx.x & 7;   // col-tile 0..7
    const int swz  = (col & 7) << 2;

    __shared__ unsigned int u_hi[1024];   // 2 buf x 16 rows(local col) x 32 u32
    __shared__ unsigned int u_lo[1024];
    for (int i = lane; i < 1024; i += 64) { u_hi[i] = 0u; u_lo[i] = 0u; }
    if (ct < 4 && lane < 16) {
        int c = ct * 16 + lane;          // global col, < 64
        u_hi[lane * 32 + (((c >> 1) & 31) ^ ((lane & 7) << 2))] =
            (c & 1) ? 0x3C000000u : 0x00003C00u;
    }

    int aoff[4][2];
#pragma unroll
    for (int tl = 0; tl < 4; ++tl)
#pragma unroll
        for (int kk = 0; kk < 2; ++kk)
            aoff[tl][kk] = (16 * tl + col) * 64 + 32 * kk + 8 * quad;

    half8 aH0[4][2], aL0[4][2], aH1[4][2], aL1[4][2];
    float4v bs0[4], bs1[4];

    auto loadA = [&](int i, half8 (&aH)[4][2], half8 (&aL)[4][2], float4v (&bs)[4]) {
        size_t base = (size_t)(chunk * TCHK + i) * 4096;
#pragma unroll
        for (int tl = 0; tl < 4; ++tl) {
#pragma unroll
            for (int kk = 0; kk < 2; ++kk) {
                aH[tl][kk] = *(const half8*)(Ahi + base + aoff[tl][kk]);
                aL[tl][kk] = *(const half8*)(Alo + base + aoff[tl][kk]);
            }
            bs[tl] = *(const float4v*)(bst + (chunk * TCHK + i) * NSTATE + 16 * tl + 4 * quad);
        }
    };

    loadA(0, aH0, aL0, bs0);
    loadA(1, aH1, aL1, bs1);

    const float4v zero4 = {0.0f, 0.0f, 0.0f, 0.0f};

    auto stepG = [&](int i, half8 (&aH)[4][2], half8 (&aL)[4][2], float4v (&bs)[4]) {
        const int cur = (i & 1) << 9;        // *512 (16 rows x 32 u32)
        const int nxt = cur ^ 512;
        const int lim = 64 + i;              // highest active column
        const int inj_ct = lim >> 4, inj_c = lim & 15;
        const bool last = (i == TCHK - 1);

        if (ct * 16 <= lim) {
            int rowb = cur + col * 32;
            uint4v uh0 = *(const uint4v*)(u_hi + rowb + (( 0 + 4 * quad) ^ swz));
            uint4v uh1 = *(const uint4v*)(u_hi + rowb + ((16 + 4 * quad) ^ swz));
            uint4v ul0 = *(const uint4v*)(u_lo + rowb + (( 0 + 4 * quad) ^ swz));
            uint4v ul1 = *(const uint4v*)(u_lo + rowb + ((16 + 4 * quad) ^ swz));
            half8 ch0 = __builtin_bit_cast(half8, uh0), ch1 = __builtin_bit_cast(half8, uh1);
            half8 cl0 = __builtin_bit_cast(half8, ul0), cl1 = __builtin_bit_cast(half8, ul1);

#pragma unroll
            for (int tl = 0; tl < 4; ++tl) {
                float4v a = zero4;
                a = __builtin_amdgcn_mfma_f32_16x16x32_f16(aH[tl][0], ch0, a, 0, 0, 0);
                a = __builtin_amdgcn_mfma_f32_16x16x32_f16(aH[tl][1], ch1, a, 0, 0, 0);
                a = __builtin_amdgcn_mfma_f32_16x16x32_f16(aH[tl][0], cl0, a, 0, 0, 0);
                a = __builtin_amdgcn_mfma_f32_16x16x32_f16(aH[tl][1], cl1, a, 0, 0, 0);
                a = __builtin_amdgcn_mfma_f32_16x16x32_f16(aL[tl][0], ch0, a, 0, 0, 0);
                a = __builtin_amdgcn_mfma_f32_16x16x32_f16(aL[tl][1], ch1, a, 0, 0, 0);
                if (ct == inj_ct && col == inj_c) a += bs[tl];

                _Float16 hx = (_Float16)a.x, hy = (_Float16)a.y;
                _Float16 hz = (_Float16)a.z, hw = (_Float16)a.w;
                _Float16 lx = (_Float16)(a.x - (float)hx), ly = (_Float16)(a.y - (float)hy);
                _Float16 lz = (_Float16)(a.z - (float)hz), lw = (_Float16)(a.w - (float)hw);
                half2s hp01; hp01.x = hx; hp01.y = hy;
                half2s hp23; hp23.x = hz; hp23.y = hw;
                half2s lp01; lp01.x = lx; lp01.y = ly;
                half2s lp23; lp23.x = lz; lp23.y = lw;
                uint2v hp = { __builtin_bit_cast(unsigned int, hp01), __builtin_bit_cast(unsigned int, hp23) };
                uint2v lp = { __builtin_bit_cast(unsigned int, lp01), __builtin_bit_cast(unsigned int, lp23) };
                *(uint2v*)(u_hi + nxt + col * 32 + ((8 * tl + 2 * quad) ^ swz)) = hp;
                *(uint2v*)(u_lo + nxt + col * 32 + ((8 * tl + 2 * quad) ^ swz)) = lp;

                size_t grow = ((size_t)(chunk * TCHK + i) * NSTATE + 16 * tl + 4 * quad) * KDIM + ct * 16 + col;
                Ghi[grow          ] = hx;
                Ghi[grow +     KDIM] = hy;
                Ghi[grow + 2 * KDIM] = hz;
                Ghi[grow + 3 * KDIM] = hw;
                if (last) {          // Glo only consumed at i=63 (boundary)
                    Glo[grow          ] = lx;
                    Glo[grow +     KDIM] = ly;
                    Glo[grow + 2 * KDIM] = lz;
                    Glo[grow + 3 * KDIM] = lw;
                }
            }
        } else {
            // inactive col-tile: write Ghi's zero tail (apply reads full KDIM)
            const _Float16 z = (_Float16)0.0f;
#pragma unroll
            for (int tl = 0; tl < 4; ++tl) {
                size_t grow = ((size_t)(chunk * TCHK + i) * NSTATE + 16 * tl + 4 * quad) * KDIM + ct * 16 + col;
                Ghi[grow          ] = z;
                Ghi[grow +     KDIM] = z;
                Ghi[grow + 2 * KDIM] = z;
                Ghi[grow + 3 * KDIM] = z;
            }
        }
        int tp = i + 2; if (tp > TCHK - 1) tp = TCHK - 1;
        loadA(tp, aH, aL, bs);
    };

    for (int i = 0; i < TCHK; i += 2) {
        stepG(i,     aH0, aL0, bs0);
        stepG(i + 1, aH1, aL1, bs1);
    }
}

// ---------------------------------------------------------------------------
// Kernel 2 v2: boundary scan, pipelined. Unchanged (verified) — still 3-term
// (errors compound over the 16-chunk recurrence, keep full precision here).
__global__ __launch_bounds__(256, 1) void boundary2_kernel(
    const float* __restrict__ inp,      // (L, NBATCH)
    const _Float16* __restrict__ Ghi,
    const _Float16* __restrict__ Glo,
    unsigned int* __restrict__ s_hi,    // (NCHK, NBATCH, 32)
    unsigned int* __restrict__ s_lo)
{
    const int tid  = threadIdx.x;
    const int lane = tid & 63;
    const int wave = tid >> 6;
    const int col  = lane & 15;
    const int quad = lane >> 4;
    const int b0   = blockIdx.x * 64;
    const int b    = b0 + wave * 16 + col;
    const int swz  = (col & 7) << 2;

    __shared__ _Float16 gstage[2][2][64][128];   // [buf][hi/lo][row][c] = 64 KB
    __shared__ float    istage[2][64][64];       // [buf][t][b-local]    = 32 KB
    __shared__ unsigned int cst[4][2][512];      // [wave][hi/lo][16 b x 32 u32] = 16 KB

    for (int i = lane; i < 512; i += 64) { cst[wave][0][i] = 0u; cst[wave][1][i] = 0u; }
    {
        const uint4v z4 = {0u, 0u, 0u, 0u};
        size_t sb = ((size_t)b) * 32 + 8 * quad;
        *(uint4v*)(s_hi + sb) = z4; *(uint4v*)(s_hi + sb + 4) = z4;
        *(uint4v*)(s_lo + sb) = z4; *(uint4v*)(s_lo + sb + 4) = z4;
    }

    half8  gr[8];
    float4v ir[4];
    auto stage_issue = [&](int k) {
        size_t base = (size_t)(k * TCHK + 63) * NSTATE * KDIM;
#pragma unroll
        for (int j = 0; j < 8; ++j) {
            int off = j * 2048 + tid * 8;
            gr[j] = (off < 8192) ? *(const half8*)(Ghi + base + off)
                                 : *(const half8*)(Glo + base + off - 8192);
        }
#pragma unroll
        for (int q2 = 0; q2 < 4; ++q2) {
            int fi   = q2 * 256 + tid;
            int tloc = fi >> 4;
            int f4   = fi & 15;
            ir[q2] = *(const float4v*)(inp + (size_t)(k * TCHK + tloc) * NBATCH + b0 + f4 * 4);
        }
    };
    auto stage_write = [&](int buf) {
#pragma unroll
        for (int j = 0; j < 8; ++j) {
            int off = j * 2048 + tid * 8;
            int reg = off >> 13;
            int loff = off & 8191;
            int row = loff >> 7;
            int c   = (loff & 127) ^ ((row & 7) << 3);
            *(half8*)&gstage[buf][reg][row][c] = gr[j];
        }
#pragma unroll
        for (int q2 = 0; q2 < 4; ++q2) {
            int fi   = q2 * 256 + tid;
            int tloc = fi >> 4;
            int f4   = fi & 15;
            *(float4v*)&istage[buf][tloc][f4 * 4] = ir[q2];
        }
    };

    const float4v zero4 = {0.0f, 0.0f, 0.0f, 0.0f};

    stage_issue(0);
    stage_write(0);
    __syncthreads();

    for (int k = 0; k < NCHK; ++k) {
        const int cur = k & 1;
        if (k < NCHK - 1) stage_issue(k + 1);

        uint4v uh0 = *(const uint4v*)(cst[wave][0] + col * 32 + (( 0 + 4 * quad) ^ swz));
        uint4v uh1 = *(const uint4v*)(cst[wave][0] + col * 32 + ((16 + 4 * quad) ^ swz));
        uint4v ul0 = *(const uint4v*)(cst[wave][1] + col * 32 + (( 0 + 4 * quad) ^ swz));
        uint4v ul1 = *(const uint4v*)(cst[wave][1] + col * 32 + ((16 + 4 * quad) ^ swz));
        half8 xh[4], xl[4];
        xh[0] = __builtin_bit_cast(half8, uh0); xh[1] = __builtin_bit_cast(half8, uh1);
        xl[0] = __builtin_bit_cast(half8, ul0); xl[1] = __builtin_bit_cast(half8, ul1);
#pragma unroll
        for (int kk2 = 0; kk2 < 2; ++kk2) {
            half8 h, l;
#pragma unroll
            for (int e = 0; e < 8; ++e) {
                float v = istage[cur][kk2 * 32 + 8 * quad + e][wave * 16 + col];
                _Float16 hh = (_Float16)v;
                h[e] = hh; l[e] = (_Float16)(v - (float)hh);
            }
            xh[2 + kk2] = h; xl[2 + kk2] = l;
        }

        float4v acc[4];
#pragma unroll
        for (int tl = 0; tl < 4; ++tl) {
            float4v a = zero4;
#pragma unroll
            for (int kk = 0; kk < 4; ++kk) {
                const int row = 16 * tl + col;
                const int c   = (32 * kk + 8 * quad) ^ ((col & 7) << 3);
                half8 gh = *(const half8*)&gstage[cur][0][row][c];
                half8 gl = *(const half8*)&gstage[cur][1][row][c];
                a = __builtin_amdgcn_mfma_f32_16x16x32_f16(gh, xh[kk], a, 0, 0, 0);
                a = __builtin_amdgcn_mfma_f32_16x16x32_f16(gh, xl[kk], a, 0, 0, 0);
                a = __builtin_amdgcn_mfma_f32_16x16x32_f16(gl, xh[kk], a, 0, 0, 0);
            }
            acc[tl] = a;
        }

        if (k < NCHK - 1) {
#pragma unroll
            for (int tl = 0; tl < 4; ++tl) {
                float4v a = acc[tl];
                _Float16 hx = (_Float16)a.x, hy = (_Float16)a.y;
                _Float16 hz = (_Float16)a.z, hw = (_Float16)a.w;
                _Float16 lx = (_Float16)(a.x - (float)hx), ly = (_Float16)(a.y - (float)hy);
                _Float16 lz = (_Float16)(a.z - (float)hz), lw = (_Float16)(a.w - (float)hw);
                half2s hp01; hp01.x = hx; hp01.y = hy;
                half2s hp23; hp23.x = hz; hp23.y = hw;
                half2s lp01; lp01.x = lx; lp01.y = ly;
                half2s lp23; lp23.x = lz; lp23.y = lw;
                uint2v hp = { __builtin_bit_cast(unsigned int, hp01), __builtin_bit_cast(unsigned int, hp23) };
                uint2v lp = { __builtin_bit_cast(unsigned int, lp01), __builtin_bit_cast(unsigned int, lp23) };
                *(uint2v*)(cst[wave][0] + col * 32 + ((8 * tl + 2 * quad) ^ swz)) = hp;
                *(uint2v*)(cst[wave][1] + col * 32 + ((8 * tl + 2 * quad) ^ swz)) = lp;
                size_t sb = ((size_t)(k + 1) * NBATCH + b) * 32 + 8 * tl + 2 * quad;
                *(uint2v*)(s_hi + sb) = hp;
                *(uint2v*)(s_lo + sb) = lp;
            }
            stage_write(cur ^ 1);
        }
        __syncthreads();
    }
}

// ---------------------------------------------------------------------------
// Kernel 3 v3: pipelined apply, 2-TERM (Ghi x Xhi + Ghi x Xlo).
// G is fp16-only here: added error |G_lo . X| ~ 1e-3 absmax, vs threshold
// 0.052. Halves G stage traffic, gbuf 64->32 KB (better occupancy), and cuts
// MFMA count 96->64 per i.
__global__ __launch_bounds__(256, 1) void apply2_kernel(
    const float* __restrict__ inp,
    const _Float16* __restrict__ Ghi,
    const unsigned int* __restrict__ s_hi,
    const unsigned int* __restrict__ s_lo,
    float* __restrict__ out)
{
    const int tid  = threadIdx.x;
    const int lane = tid & 63;
    const int wave = tid >> 6;
    const int col  = lane & 15;
    const int quad = lane >> 4;

    const int virt  = (blockIdx.x & 7) * 256 + (blockIdx.x >> 3);
    const int chunk = virt >> 7;
    const int ig    = (virt >> 4) & 7;
    const int bt    = virt & 15;

    __shared__ _Float16 gbuf[2][16][64][8];   // 32 KB (hi only)

    int bb[2];
    bb[0] = bt * 128 + wave * 32 + col;
    bb[1] = bb[0] + 16;
    half8 xh[2][4], xl[2][4];
#pragma unroll
    for (int bs = 0; bs < 2; ++bs) {
        size_t sb = ((size_t)chunk * NBATCH + bb[bs]) * 32;
        uint4v sh0 = *(const uint4v*)(s_hi + sb +  0 + 4 * quad);
        uint4v sh1 = *(const uint4v*)(s_hi + sb + 16 + 4 * quad);
        uint4v sl0 = *(const uint4v*)(s_lo + sb +  0 + 4 * quad);
        uint4v sl1 = *(const uint4v*)(s_lo + sb + 16 + 4 * quad);
        xh[bs][0] = __builtin_bit_cast(half8, sh0); xh[bs][1] = __builtin_bit_cast(half8, sh1);
        xl[bs][0] = __builtin_bit_cast(half8, sl0); xl[bs][1] = __builtin_bit_cast(half8, sl1);
#pragma unroll
        for (int kk2 = 0; kk2 < 2; ++kk2) {
            half8 h, l;
#pragma unroll
            for (int e = 0; e < 8; ++e) {
                float v = inp[(size_t)(chunk * TCHK + kk2 * 32 + 8 * quad + e) * NBATCH + bb[bs]];
                _Float16 hh = (_Float16)v;
                h[e] = hh; l[e] = (_Float16)(v - (float)hh);
            }
            xh[bs][2 + kk2] = h; xl[bs][2 + kk2] = l;
        }
    }

    half8 sreg[4];
    auto stage_issue = [&](int i) {
        size_t base = ((size_t)(chunk * TCHK + ig * 8 + i) * NSTATE + 16 * wave + col) * KDIM + 8 * quad;
#pragma unroll
        for (int kk = 0; kk < 4; ++kk)
            sreg[kk] = *(const half8*)(Ghi + base + 32 * kk);
    };
    auto stage_write = [&](int buf) {
#pragma unroll
        for (int kk = 0; kk < 4; ++kk)
            *(half8*)&gbuf[buf][wave * 4 + kk][lane][0] = sreg[kk];
    };

    const float4v zero4 = {0.0f, 0.0f, 0.0f, 0.0f};
    float4v* outv = (float4v*)out;

    stage_issue(0);
    stage_write(0);
    __syncthreads();

    for (int i = 0; i < 8; ++i) {
        const int cur = i & 1;
        if (i < 7) stage_issue(i + 1);

        float4v acc[2][4];
#pragma unroll
        for (int bs = 0; bs < 2; ++bs)
#pragma unroll
            for (int tl = 0; tl < 4; ++tl) acc[bs][tl] = zero4;

#pragma unroll
        for (int kk = 0; kk < 4; ++kk) {
            half8 gh[4];
#pragma unroll
            for (int tl = 0; tl < 4; ++tl)
                gh[tl] = *(const half8*)&gbuf[cur][tl * 4 + kk][lane][0];
#pragma unroll
            for (int tl = 0; tl < 4; ++tl) {
#pragma unroll
                for (int bs = 0; bs < 2; ++bs) {
                    acc[bs][tl] = __builtin_amdgcn_mfma_f32_16x16x32_f16(gh[tl], xh[bs][kk], acc[bs][tl], 0, 0, 0);
                    acc[bs][tl] = __builtin_amdgcn_mfma_f32_16x16x32_f16(gh[tl], xl[bs][kk], acc[bs][tl], 0, 0, 0);
                }
            }
        }

        const size_t tt = (size_t)(chunk * TCHK + ig * 8 + i);
#pragma unroll
        for (int bs = 0; bs < 2; ++bs)
#pragma unroll
            for (int tl = 0; tl < 4; ++tl)
                outv[(tt * NBATCH + bb[bs]) * 16 + 4 * tl + quad] = acc[bs][tl];

        if (i < 7) stage_write(cur ^ 1);
        __syncthreads();
    }
}

// ---------------------------------------------------------------------------
// R3 fallback: sequential per-step scan (verified passing).
template <bool USE_WS>
__global__ __launch_bounds__(64, 1) void hippo_scan_kernel(
    const float* __restrict__ inp, const float* __restrict__ bst,
    const float* __restrict__ A32, const _Float16* __restrict__ Ahi,
    const _Float16* __restrict__ Alo, float* __restrict__ out)
{
    const int lane = threadIdx.x;
    const int col  = lane & 15;
    const int quad = lane >> 4;
    const int b0   = blockIdx.x * 16;
    const int swz  = (col & 7) << 2;

    __shared__ unsigned int c_hi[1024];
    __shared__ unsigned int c_lo[1024];
    for (int i = lane; i < 1024; i += 64) { c_hi[i] = 0u; c_lo[i] = 0u; }

    const int rd0 = col * 32 + (( 0 + 4 * quad) ^ swz);
    const int rd1 = col * 32 + ((16 + 4 * quad) ^ swz);
    int wr[4];
#pragma unroll
    for (int ts = 0; ts < 4; ++ts) wr[ts] = col * 32 + ((8 * ts + 2 * quad) ^ swz);

    int aoff[4][2];
#pragma unroll
    for (int tl = 0; tl < 4; ++tl)
#pragma unroll
        for (int kk = 0; kk < 2; ++kk)
            aoff[tl][kk] = (16 * tl + col) * 64 + 32 * kk + 8 * quad;

    half8 ah0[4][2], al0[4][2], ah1[4][2], al1[4][2];
    float inp0, inp1;
    float4v bst0[4], bst1[4];

    auto load_set = [&](int t, half8 (&ah)[4][2], half8 (&al)[4][2],
                        float4v (&bstv)[4], float& inpv) {
#pragma unroll
        for (int tl = 0; tl < 4; ++tl) {
#pragma unroll
            for (int kk = 0; kk < 2; ++kk) {
                if constexpr (USE_WS) {
                    ah[tl][kk] = *(const half8*)(Ahi + (size_t)t * 4096 + aoff[tl][kk]);
                    al[tl][kk] = *(const half8*)(Alo + (size_t)t * 4096 + aoff[tl][kk]);
                } else {
                    const float* p = A32 + (size_t)t * 4096 + aoff[tl][kk];
                    float4v f0 = *(const float4v*)(p);
                    float4v f1 = *(const float4v*)(p + 4);
                    half8 h, l;
#pragma unroll
                    for (int e = 0; e < 4; ++e) {
                        float v0 = f0[e], v1 = f1[e];
                        _Float16 h0 = (_Float16)v0, h1 = (_Float16)v1;
                        h[e] = h0; h[e + 4] = h1;
                        l[e] = (_Float16)(v0 - (float)h0);
                        l[e + 4] = (_Float16)(v1 - (float)h1);
                    }
                    ah[tl][kk] = h; al[tl][kk] = l;
                }
            }
        }
        inpv = inp[t * NBATCH + b0 + col];
#pragma unroll
        for (int tl = 0; tl < 4; ++tl)
            bstv[tl] = *(const float4v*)(bst + t * NSTATE + 16 * tl + 4 * quad);
    };

    load_set(0, ah0, al0, bst0, inp0);
    load_set(1, ah1, al1, bst1, inp1);
    const float4v zero4 = {0.0f, 0.0f, 0.0f, 0.0f};

    auto step = [&](int t, int cur, half8 (&ah)[4][2], half8 (&al)[4][2],
                    float4v (&bstv)[4], float& inpv) {
        const int nxt = cur ^ 512;
        uint4v u_h0 = *(const uint4v*)(c_hi + cur + rd0);
        uint4v u_h1 = *(const uint4v*)(c_hi + cur + rd1);
        uint4v u_l0 = *(const uint4v*)(c_lo + cur + rd0);
        uint4v u_l1 = *(const uint4v*)(c_lo + cur + rd1);
        half8 ch[2] = { __builtin_bit_cast(half8, u_h0), __builtin_bit_cast(half8, u_h1) };
        half8 cl[2] = { __builtin_bit_cast(half8, u_l0), __builtin_bit_cast(half8, u_l1) };

        float4v acc[4];
#pragma unroll
        for (int tl = 0; tl < 4; ++tl) {
            float4v accA = bstv[tl] * inpv;
            accA = __builtin_amdgcn_mfma_f32_16x16x32_f16(ah[tl][0], ch[0], accA, 0, 0, 0);
            accA = __builtin_amdgcn_mfma_f32_16x16x32_f16(ah[tl][1], ch[1], accA, 0, 0, 0);
            float4v accB = __builtin_amdgcn_mfma_f32_16x16x32_f16(ah[tl][0], cl[0], zero4, 0, 0, 0);
            accB = __builtin_amdgcn_mfma_f32_16x16x32_f16(ah[tl][1], cl[1], accB, 0, 0, 0);
            accB = __builtin_amdgcn_mfma_f32_16x16x32_f16(al[tl][0], ch[0], accB, 0, 0, 0);
            accB = __builtin_amdgcn_mfma_f32_16x16x32_f16(al[tl][1], ch[1], accB, 0, 0, 0);
            acc[tl] = accA + accB;
        }

        float4v* outv = (float4v*)out;
#pragma unroll
        for (int tl = 0; tl < 4; ++tl)
            outv[(size_t)(t * NBATCH + b0 + col) * 16 + 4 * tl + quad] = acc[tl];

        int tp = t + 2; if (tp > L_SEQ - 1) tp = L_SEQ - 1;
        load_set(tp, ah, al, bstv, inpv);

#pragma unroll
        for (int tl = 0; tl < 4; ++tl) {
            float x = acc[tl].x, y = acc[tl].y, z = acc[tl].z, w = acc[tl].w;
            _Float16 hx = (_Float16)x, hy = (_Float16)y, hz = (_Float16)z, hw = (_Float16)w;
            half2s hp01; hp01.x = hx; hp01.y = hy;
            half2s hp23; hp23.x = hz; hp23.y = hw;
            half2s lp01; lp01.x = (_Float16)(x - (float)hx); lp01.y = (_Float16)(y - (float)hy);
            half2s lp23; lp23.x = (_Float16)(z - (float)hz); lp23.y = (_Float16)(w - (float)hw);
            uint2v hp = { __builtin_bit_cast(unsigned int, hp01), __builtin_bit_cast(unsigned int, hp23) };
            uint2v lp = { __builtin_bit_cast(unsigned int, lp01), __builtin_bit_cast(unsigned int, lp23) };
            *(uint2v*)(c_hi + nxt + wr[tl]) = hp;
            *(uint2v*)(c_lo + nxt + wr[tl]) = lp;
        }
    };

    for (int t = 0; t < L_SEQ; t += 2) {
        step(t,     0,   ah0, al0, bst0, inp0);
        step(t + 1, 512, ah1, al1, bst1, inp1);
    }
}

// ---------------------------------------------------------------------------
extern "C" void kernel_launch(void* const* d_in, const int* in_sizes, int n_in,
                              void* d_out, int out_size, void* d_ws, size_t ws_size,
                              hipStream_t stream) {
    const float* inputs = (const float*)d_in[0];
    const float* A_st   = (const float*)d_in[1];
    const float* B_st   = (const float*)d_in[2];
    float* out = (float*)d_out;

    const size_t n_a    = (size_t)L_SEQ * NSTATE * NSTATE;
    const size_t SZ_A   = n_a * sizeof(_Float16);                                 // 8 MB
    const size_t SZ_G   = (size_t)NCHK * TCHK * NSTATE * KDIM * sizeof(_Float16); // 16 MB
    const size_t SZ_S   = (size_t)NCHK * NBATCH * 32 * sizeof(unsigned int);      // 4 MB
    const size_t OFF_ALO = SZ_A;
    const size_t OFF_GHI = 2 * SZ_A;
    const size_t OFF_GLO = OFF_GHI + SZ_G;
    const size_t OFF_SHI = OFF_GLO + SZ_G;
    const size_t OFF_SLO = OFF_SHI + SZ_S;
    const size_t NEED    = OFF_SLO + SZ_S;                                        // 56 MB

    if (ws_size >= NEED) {
        char* ws = (char*)d_ws;
        _Float16* Ahi = (_Float16*)ws;
        _Float16* Alo = (_Float16*)(ws + OFF_ALO);
        _Float16* Ghi = (_Float16*)(ws + OFF_GHI);
        _Float16* Glo = (_Float16*)(ws + OFF_GLO);
        unsigned int* shi = (unsigned int*)(ws + OFF_SHI);
        unsigned int* slo = (unsigned int*)(ws + OFF_SLO);

        split_A_kernel<<<(int)(n_a / 256), 256, 0, stream>>>(A_st, Ahi, Alo);
        build_G_kernel<<<NCHK * 8, 64, 0, stream>>>(Ahi, Alo, B_st, Ghi, Glo);
        boundary2_kernel<<<NBATCH / 64, 256, 0, stream>>>(inputs, Ghi, Glo, shi, slo);
        apply2_kernel<<<NCHK * 8 * 16, 256, 0, stream>>>(inputs, Ghi, shi, slo, out);
    } else if (ws_size >= 2 * SZ_A) {
        _Float16* Ahi = (_Float16*)d_ws;
        _Float16* Alo = Ahi + n_a;
        split_A_kernel<<<(int)(n_a / 256), 256, 0, stream>>>(A_st, Ahi, Alo);
        hippo_scan_kernel<true><<<NBATCH / 16, 64, 0, stream>>>(inputs, B_st, A_st, Ahi, Alo, out);
    } else {
        hippo_scan_kernel<false><<<NBATCH / 16, 64, 0, stream>>>(inputs, B_st, A_st, nullptr, nullptr, out);
    }
}

// Round 13
// 219.898 us; speedup vs baseline: 2.0266x; 1.0041x over previous
//
#include <hip/hip_runtime.h>
#include <hip/hip_fp16.h>

#define L_SEQ  1024
#define NBATCH 2048
#define NSTATE 64
#define TCHK   64
#define NCHK   16    // L_SEQ / TCHK
#define KDIM   128   // NSTATE + TCHK

typedef _Float16 half8  __attribute__((ext_vector_type(8)));
typedef _Float16 half2s __attribute__((ext_vector_type(2)));
typedef float    float4v __attribute__((ext_vector_type(4)));
typedef unsigned int uint2v __attribute__((ext_vector_type(2)));
typedef unsigned int uint4v __attribute__((ext_vector_type(4)));

// Relaxed block barrier: orders LDS traffic only (lgkmcnt), does NOT drain
// vmcnt — global out-stores stay in flight across iterations. The G-load ->
// ds_write dependence is enforced by the compiler's precise register vmcnt.
__device__ inline void barrier_lds_only() {
    asm volatile("s_waitcnt lgkmcnt(0)" ::: "memory");
    __builtin_amdgcn_s_barrier();
}

// ---------------------------------------------------------------------------
__global__ __launch_bounds__(256) void split_A_kernel(const float* __restrict__ A,
                                                      _Float16* __restrict__ hi,
                                                      _Float16* __restrict__ lo) {
    int i = blockIdx.x * 256 + threadIdx.x;
    float a = A[i];
    _Float16 h = (_Float16)a;
    hi[i] = h;
    lo[i] = (_Float16)(a - (float)h);
}

// ---------------------------------------------------------------------------
// Kernel 1 v6: build G — 128 one-wave blocks (chunk, col-tile), fused zero
// tail, Glo stored only at i=63. Unchanged (verified R12).
__global__ __launch_bounds__(64, 1) void build_G_kernel(
    const _Float16* __restrict__ Ahi,   // (L, 64, 64)
    const _Float16* __restrict__ Alo,
    const float* __restrict__ bst,      // (L, 64)
    _Float16* __restrict__ Ghi,         // (NCHK, 64*64, 128) row-major
    _Float16* __restrict__ Glo)         // only rowblock i=63 per chunk is valid
{
    const int lane = threadIdx.x;
    const int col  = lane & 15;
    const int quad = lane >> 4;
    const int chunk = blockIdx.x >> 3;
    const int ct    = blockIdx.x & 7;   // col-tile 0..7
    const int swz  = (col & 7) << 2;

    __shared__ unsigned int u_hi[1024];   // 2 buf x 16 rows(local col) x 32 u32
    __shared__ unsigned int u_lo[1024];
    for (int i = lane; i < 1024; i += 64) { u_hi[i] = 0u; u_lo[i] = 0u; }
    if (ct < 4 && lane < 16) {
        int c = ct * 16 + lane;          // global col, < 64
        u_hi[lane * 32 + (((c >> 1) & 31) ^ ((lane & 7) << 2))] =
            (c & 1) ? 0x3C000000u : 0x00003C00u;
    }

    int aoff[4][2];
#pragma unroll
    for (int tl = 0; tl < 4; ++tl)
#pragma unroll
        for (int kk = 0; kk < 2; ++kk)
            aoff[tl][kk] = (16 * tl + col) * 64 + 32 * kk + 8 * quad;

    half8 aH0[4][2], aL0[4][2], aH1[4][2], aL1[4][2];
    float4v bs0[4], bs1[4];

    auto loadA = [&](int i, half8 (&aH)[4][2], half8 (&aL)[4][2], float4v (&bs)[4]) {
        size_t base = (size_t)(chunk * TCHK + i) * 4096;
#pragma unroll
        for (int tl = 0; tl < 4; ++tl) {
#pragma unroll
            for (int kk = 0; kk < 2; ++kk) {
                aH[tl][kk] = *(const half8*)(Ahi + base + aoff[tl][kk]);
                aL[tl][kk] = *(const half8*)(Alo + base + aoff[tl][kk]);
            }
            bs[tl] = *(const float4v*)(bst + (chunk * TCHK + i) * NSTATE + 16 * tl + 4 * quad);
        }
    };

    loadA(0, aH0, aL0, bs0);
    loadA(1, aH1, aL1, bs1);

    const float4v zero4 = {0.0f, 0.0f, 0.0f, 0.0f};

    auto stepG = [&](int i, half8 (&aH)[4][2], half8 (&aL)[4][2], float4v (&bs)[4]) {
        const int cur = (i & 1) << 9;        // *512 (16 rows x 32 u32)
        const int nxt = cur ^ 512;
        const int lim = 64 + i;              // highest active column
        const int inj_ct = lim >> 4, inj_c = lim & 15;
        const bool last = (i == TCHK - 1);

        if (ct * 16 <= lim) {
            int rowb = cur + col * 32;
            uint4v uh0 = *(const uint4v*)(u_hi + rowb + (( 0 + 4 * quad) ^ swz));
            uint4v uh1 = *(const uint4v*)(u_hi + rowb + ((16 + 4 * quad) ^ swz));
            uint4v ul0 = *(const uint4v*)(u_lo + rowb + (( 0 + 4 * quad) ^ swz));
            uint4v ul1 = *(const uint4v*)(u_lo + rowb + ((16 + 4 * quad) ^ swz));
            half8 ch0 = __builtin_bit_cast(half8, uh0), ch1 = __builtin_bit_cast(half8, uh1);
            half8 cl0 = __builtin_bit_cast(half8, ul0), cl1 = __builtin_bit_cast(half8, ul1);

#pragma unroll
            for (int tl = 0; tl < 4; ++tl) {
                float4v a = zero4;
                a = __builtin_amdgcn_mfma_f32_16x16x32_f16(aH[tl][0], ch0, a, 0, 0, 0);
                a = __builtin_amdgcn_mfma_f32_16x16x32_f16(aH[tl][1], ch1, a, 0, 0, 0);
                a = __builtin_amdgcn_mfma_f32_16x16x32_f16(aH[tl][0], cl0, a, 0, 0, 0);
                a = __builtin_amdgcn_mfma_f32_16x16x32_f16(aH[tl][1], cl1, a, 0, 0, 0);
                a = __builtin_amdgcn_mfma_f32_16x16x32_f16(aL[tl][0], ch0, a, 0, 0, 0);
                a = __builtin_amdgcn_mfma_f32_16x16x32_f16(aL[tl][1], ch1, a, 0, 0, 0);
                if (ct == inj_ct && col == inj_c) a += bs[tl];

                _Float16 hx = (_Float16)a.x, hy = (_Float16)a.y;
                _Float16 hz = (_Float16)a.z, hw = (_Float16)a.w;
                _Float16 lx = (_Float16)(a.x - (float)hx), ly = (_Float16)(a.y - (float)hy);
                _Float16 lz = (_Float16)(a.z - (float)hz), lw = (_Float16)(a.w - (float)hw);
                half2s hp01; hp01.x = hx; hp01.y = hy;
                half2s hp23; hp23.x = hz; hp23.y = hw;
                half2s lp01; lp01.x = lx; lp01.y = ly;
                half2s lp23; lp23.x = lz; lp23.y = lw;
                uint2v hp = { __builtin_bit_cast(unsigned int, hp01), __builtin_bit_cast(unsigned int, hp23) };
                uint2v lp = { __builtin_bit_cast(unsigned int, lp01), __builtin_bit_cast(unsigned int, lp23) };
                *(uint2v*)(u_hi + nxt + col * 32 + ((8 * tl + 2 * quad) ^ swz)) = hp;
                *(uint2v*)(u_lo + nxt + col * 32 + ((8 * tl + 2 * quad) ^ swz)) = lp;

                size_t grow = ((size_t)(chunk * TCHK + i) * NSTATE + 16 * tl + 4 * quad) * KDIM + ct * 16 + col;
                Ghi[grow          ] = hx;
                Ghi[grow +     KDIM] = hy;
                Ghi[grow + 2 * KDIM] = hz;
                Ghi[grow + 3 * KDIM] = hw;
                if (last) {          // Glo only consumed at i=63 (boundary)
                    Glo[grow          ] = lx;
                    Glo[grow +     KDIM] = ly;
                    Glo[grow + 2 * KDIM] = lz;
                    Glo[grow + 3 * KDIM] = lw;
                }
            }
        } else {
            // inactive col-tile: write Ghi's zero tail (apply reads full KDIM)
            const _Float16 z = (_Float16)0.0f;
#pragma unroll
            for (int tl = 0; tl < 4; ++tl) {
                size_t grow = ((size_t)(chunk * TCHK + i) * NSTATE + 16 * tl + 4 * quad) * KDIM + ct * 16 + col;
                Ghi[grow          ] = z;
                Ghi[grow +     KDIM] = z;
                Ghi[grow + 2 * KDIM] = z;
                Ghi[grow + 3 * KDIM] = z;
            }
        }
        int tp = i + 2; if (tp > TCHK - 1) tp = TCHK - 1;
        loadA(tp, aH, aL, bs);
    };

    for (int i = 0; i < TCHK; i += 2) {
        stepG(i,     aH0, aL0, bs0);
        stepG(i + 1, aH1, aL1, bs1);
    }
}

// ---------------------------------------------------------------------------
// Kernel 2 v2: boundary scan, pipelined, 3-term. Unchanged (verified).
__global__ __launch_bounds__(256, 1) void boundary2_kernel(
    const float* __restrict__ inp,      // (L, NBATCH)
    const _Float16* __restrict__ Ghi,
    const _Float16* __restrict__ Glo,
    unsigned int* __restrict__ s_hi,    // (NCHK, NBATCH, 32)
    unsigned int* __restrict__ s_lo)
{
    const int tid  = threadIdx.x;
    const int lane = tid & 63;
    const int wave = tid >> 6;
    const int col  = lane & 15;
    const int quad = lane >> 4;
    const int b0   = blockIdx.x * 64;
    const int b    = b0 + wave * 16 + col;
    const int swz  = (col & 7) << 2;

    __shared__ _Float16 gstage[2][2][64][128];   // [buf][hi/lo][row][c] = 64 KB
    __shared__ float    istage[2][64][64];       // [buf][t][b-local]    = 32 KB
    __shared__ unsigned int cst[4][2][512];      // [wave][hi/lo][16 b x 32 u32] = 16 KB

    for (int i = lane; i < 512; i += 64) { cst[wave][0][i] = 0u; cst[wave][1][i] = 0u; }
    {
        const uint4v z4 = {0u, 0u, 0u, 0u};
        size_t sb = ((size_t)b) * 32 + 8 * quad;
        *(uint4v*)(s_hi + sb) = z4; *(uint4v*)(s_hi + sb + 4) = z4;
        *(uint4v*)(s_lo + sb) = z4; *(uint4v*)(s_lo + sb + 4) = z4;
    }

    half8  gr[8];
    float4v ir[4];
    auto stage_issue = [&](int k) {
        size_t base = (size_t)(k * TCHK + 63) * NSTATE * KDIM;
#pragma unroll
        for (int j = 0; j < 8; ++j) {
            int off = j * 2048 + tid * 8;
            gr[j] = (off < 8192) ? *(const half8*)(Ghi + base + off)
                                 : *(const half8*)(Glo + base + off - 8192);
        }
#pragma unroll
        for (int q2 = 0; q2 < 4; ++q2) {
            int fi   = q2 * 256 + tid;
            int tloc = fi >> 4;
            int f4   = fi & 15;
            ir[q2] = *(const float4v*)(inp + (size_t)(k * TCHK + tloc) * NBATCH + b0 + f4 * 4);
        }
    };
    auto stage_write = [&](int buf) {
#pragma unroll
        for (int j = 0; j < 8; ++j) {
            int off = j * 2048 + tid * 8;
            int reg = off >> 13;
            int loff = off & 8191;
            int row = loff >> 7;
            int c   = (loff & 127) ^ ((row & 7) << 3);
            *(half8*)&gstage[buf][reg][row][c] = gr[j];
        }
#pragma unroll
        for (int q2 = 0; q2 < 4; ++q2) {
            int fi   = q2 * 256 + tid;
            int tloc = fi >> 4;
            int f4   = fi & 15;
            *(float4v*)&istage[buf][tloc][f4 * 4] = ir[q2];
        }
    };

    const float4v zero4 = {0.0f, 0.0f, 0.0f, 0.0f};

    stage_issue(0);
    stage_write(0);
    __syncthreads();

    for (int k = 0; k < NCHK; ++k) {
        const int cur = k & 1;
        if (k < NCHK - 1) stage_issue(k + 1);

        uint4v uh0 = *(const uint4v*)(cst[wave][0] + col * 32 + (( 0 + 4 * quad) ^ swz));
        uint4v uh1 = *(const uint4v*)(cst[wave][0] + col * 32 + ((16 + 4 * quad) ^ swz));
        uint4v ul0 = *(const uint4v*)(cst[wave][1] + col * 32 + (( 0 + 4 * quad) ^ swz));
        uint4v ul1 = *(const uint4v*)(cst[wave][1] + col * 32 + ((16 + 4 * quad) ^ swz));
        half8 xh[4], xl[4];
        xh[0] = __builtin_bit_cast(half8, uh0); xh[1] = __builtin_bit_cast(half8, uh1);
        xl[0] = __builtin_bit_cast(half8, ul0); xl[1] = __builtin_bit_cast(half8, ul1);
#pragma unroll
        for (int kk2 = 0; kk2 < 2; ++kk2) {
            half8 h, l;
#pragma unroll
            for (int e = 0; e < 8; ++e) {
                float v = istage[cur][kk2 * 32 + 8 * quad + e][wave * 16 + col];
                _Float16 hh = (_Float16)v;
                h[e] = hh; l[e] = (_Float16)(v - (float)hh);
            }
            xh[2 + kk2] = h; xl[2 + kk2] = l;
        }

        float4v acc[4];
#pragma unroll
        for (int tl = 0; tl < 4; ++tl) {
            float4v a = zero4;
#pragma unroll
            for (int kk = 0; kk < 4; ++kk) {
                const int row = 16 * tl + col;
                const int c   = (32 * kk + 8 * quad) ^ ((col & 7) << 3);
                half8 gh = *(const half8*)&gstage[cur][0][row][c];
                half8 gl = *(const half8*)&gstage[cur][1][row][c];
                a = __builtin_amdgcn_mfma_f32_16x16x32_f16(gh, xh[kk], a, 0, 0, 0);
                a = __builtin_amdgcn_mfma_f32_16x16x32_f16(gh, xl[kk], a, 0, 0, 0);
                a = __builtin_amdgcn_mfma_f32_16x16x32_f16(gl, xh[kk], a, 0, 0, 0);
            }
            acc[tl] = a;
        }

        if (k < NCHK - 1) {
#pragma unroll
            for (int tl = 0; tl < 4; ++tl) {
                float4v a = acc[tl];
                _Float16 hx = (_Float16)a.x, hy = (_Float16)a.y;
                _Float16 hz = (_Float16)a.z, hw = (_Float16)a.w;
                _Float16 lx = (_Float16)(a.x - (float)hx), ly = (_Float16)(a.y - (float)hy);
                _Float16 lz = (_Float16)(a.z - (float)hz), lw = (_Float16)(a.w - (float)hw);
                half2s hp01; hp01.x = hx; hp01.y = hy;
                half2s hp23; hp23.x = hz; hp23.y = hw;
                half2s lp01; lp01.x = lx; lp01.y = ly;
                half2s lp23; lp23.x = lz; lp23.y = lw;
                uint2v hp = { __builtin_bit_cast(unsigned int, hp01), __builtin_bit_cast(unsigned int, hp23) };
                uint2v lp = { __builtin_bit_cast(unsigned int, lp01), __builtin_bit_cast(unsigned int, lp23) };
                *(uint2v*)(cst[wave][0] + col * 32 + ((8 * tl + 2 * quad) ^ swz)) = hp;
                *(uint2v*)(cst[wave][1] + col * 32 + ((8 * tl + 2 * quad) ^ swz)) = lp;
                size_t sb = ((size_t)(k + 1) * NBATCH + b) * 32 + 8 * tl + 2 * quad;
                *(uint2v*)(s_hi + sb) = hp;
                *(uint2v*)(s_lo + sb) = lp;
            }
            stage_write(cur ^ 1);
        }
        __syncthreads();
    }
}

// ---------------------------------------------------------------------------
// Kernel 3 v4: pipelined apply, 2-term, RELAXED BARRIER.
// The inter-iteration hazard is LDS-only (all waves done reading gbuf[cur] and
// writing gbuf[cur^1]); out-stores gate nothing. barrier_lds_only() waits
// lgkmcnt(0) + s_barrier WITHOUT vmcnt(0), so the 512 MB out-store stream
// stays in flight across iterations instead of draining at every barrier.
__global__ __launch_bounds__(256, 1) void apply2_kernel(
    const float* __restrict__ inp,
    const _Float16* __restrict__ Ghi,
    const unsigned int* __restrict__ s_hi,
    const unsigned int* __restrict__ s_lo,
    float* __restrict__ out)
{
    const int tid  = threadIdx.x;
    const int lane = tid & 63;
    const int wave = tid >> 6;
    const int col  = lane & 15;
    const int quad = lane >> 4;

    const int virt  = (blockIdx.x & 7) * 256 + (blockIdx.x >> 3);
    const int chunk = virt >> 7;
    const int ig    = (virt >> 4) & 7;
    const int bt    = virt & 15;

    __shared__ _Float16 gbuf[2][16][64][8];   // 32 KB (hi only)

    int bb[2];
    bb[0] = bt * 128 + wave * 32 + col;
    bb[1] = bb[0] + 16;
    half8 xh[2][4], xl[2][4];
#pragma unroll
    for (int bs = 0; bs < 2; ++bs) {
        size_t sb = ((size_t)chunk * NBATCH + bb[bs]) * 32;
        uint4v sh0 = *(const uint4v*)(s_hi + sb +  0 + 4 * quad);
        uint4v sh1 = *(const uint4v*)(s_hi + sb + 16 + 4 * quad);
        uint4v sl0 = *(const uint4v*)(s_lo + sb +  0 + 4 * quad);
        uint4v sl1 = *(const uint4v*)(s_lo + sb + 16 + 4 * quad);
        xh[bs][0] = __builtin_bit_cast(half8, sh0); xh[bs][1] = __builtin_bit_cast(half8, sh1);
        xl[bs][0] = __builtin_bit_cast(half8, sl0); xl[bs][1] = __builtin_bit_cast(half8, sl1);
#pragma unroll
        for (int kk2 = 0; kk2 < 2; ++kk2) {
            half8 h, l;
#pragma unroll
            for (int e = 0; e < 8; ++e) {
                float v = inp[(size_t)(chunk * TCHK + kk2 * 32 + 8 * quad + e) * NBATCH + bb[bs]];
                _Float16 hh = (_Float16)v;
                h[e] = hh; l[e] = (_Float16)(v - (float)hh);
            }
            xh[bs][2 + kk2] = h; xl[bs][2 + kk2] = l;
        }
    }

    half8 sreg[4];
    auto stage_issue = [&](int i) {
        size_t base = ((size_t)(chunk * TCHK + ig * 8 + i) * NSTATE + 16 * wave + col) * KDIM + 8 * quad;
#pragma unroll
        for (int kk = 0; kk < 4; ++kk)
            sreg[kk] = *(const half8*)(Ghi + base + 32 * kk);
    };
    auto stage_write = [&](int buf) {
#pragma unroll
        for (int kk = 0; kk < 4; ++kk)
            *(half8*)&gbuf[buf][wave * 4 + kk][lane][0] = sreg[kk];
    };

    const float4v zero4 = {0.0f, 0.0f, 0.0f, 0.0f};
    float4v* outv = (float4v*)out;

    stage_issue(0);
    stage_write(0);
    barrier_lds_only();

    for (int i = 0; i < 8; ++i) {
        const int cur = i & 1;
        if (i < 7) stage_issue(i + 1);

        float4v acc[2][4];
#pragma unroll
        for (int bs = 0; bs < 2; ++bs)
#pragma unroll
            for (int tl = 0; tl < 4; ++tl) acc[bs][tl] = zero4;

#pragma unroll
        for (int kk = 0; kk < 4; ++kk) {
            half8 gh[4];
#pragma unroll
            for (int tl = 0; tl < 4; ++tl)
                gh[tl] = *(const half8*)&gbuf[cur][tl * 4 + kk][lane][0];
#pragma unroll
            for (int tl = 0; tl < 4; ++tl) {
#pragma unroll
                for (int bs = 0; bs < 2; ++bs) {
                    acc[bs][tl] = __builtin_amdgcn_mfma_f32_16x16x32_f16(gh[tl], xh[bs][kk], acc[bs][tl], 0, 0, 0);
                    acc[bs][tl] = __builtin_amdgcn_mfma_f32_16x16x32_f16(gh[tl], xl[bs][kk], acc[bs][tl], 0, 0, 0);
                }
            }
        }

        const size_t tt = (size_t)(chunk * TCHK + ig * 8 + i);
#pragma unroll
        for (int bs = 0; bs < 2; ++bs)
#pragma unroll
            for (int tl = 0; tl < 4; ++tl)
                outv[(tt * NBATCH + bb[bs]) * 16 + 4 * tl + quad] = acc[bs][tl];

        if (i < 7) stage_write(cur ^ 1);   // compiler inserts precise vmcnt for sreg
        barrier_lds_only();                 // LDS-only drain; stores stay in flight
    }
}

// ---------------------------------------------------------------------------
// R3 fallback: sequential per-step scan (verified passing).
template <bool USE_WS>
__global__ __launch_bounds__(64, 1) void hippo_scan_kernel(
    const float* __restrict__ inp, const float* __restrict__ bst,
    const float* __restrict__ A32, const _Float16* __restrict__ Ahi,
    const _Float16* __restrict__ Alo, float* __restrict__ out)
{
    const int lane = threadIdx.x;
    const int col  = lane & 15;
    const int quad = lane >> 4;
    const int b0   = blockIdx.x * 16;
    const int swz  = (col & 7) << 2;

    __shared__ unsigned int c_hi[1024];
    __shared__ unsigned int c_lo[1024];
    for (int i = lane; i < 1024; i += 64) { c_hi[i] = 0u; c_lo[i] = 0u; }

    const int rd0 = col * 32 + (( 0 + 4 * quad) ^ swz);
    const int rd1 = col * 32 + ((16 + 4 * quad) ^ swz);
    int wr[4];
#pragma unroll
    for (int ts = 0; ts < 4; ++ts) wr[ts] = col * 32 + ((8 * ts + 2 * quad) ^ swz);

    int aoff[4][2];
#pragma unroll
    for (int tl = 0; tl < 4; ++tl)
#pragma unroll
        for (int kk = 0; kk < 2; ++kk)
            aoff[tl][kk] = (16 * tl + col) * 64 + 32 * kk + 8 * quad;

    half8 ah0[4][2], al0[4][2], ah1[4][2], al1[4][2];
    float inp0, inp1;
    float4v bst0[4], bst1[4];

    auto load_set = [&](int t, half8 (&ah)[4][2], half8 (&al)[4][2],
                        float4v (&bstv)[4], float& inpv) {
#pragma unroll
        for (int tl = 0; tl < 4; ++tl) {
#pragma unroll
            for (int kk = 0; kk < 2; ++kk) {
                if constexpr (USE_WS) {
                    ah[tl][kk] = *(const half8*)(Ahi + (size_t)t * 4096 + aoff[tl][kk]);
                    al[tl][kk] = *(const half8*)(Alo + (size_t)t * 4096 + aoff[tl][kk]);
                } else {
                    const float* p = A32 + (size_t)t * 4096 + aoff[tl][kk];
                    float4v f0 = *(const float4v*)(p);
                    float4v f1 = *(const float4v*)(p + 4);
                    half8 h, l;
#pragma unroll
                    for (int e = 0; e < 4; ++e) {
                        float v0 = f0[e], v1 = f1[e];
                        _Float16 h0 = (_Float16)v0, h1 = (_Float16)v1;
                        h[e] = h0; h[e + 4] = h1;
                        l[e] = (_Float16)(v0 - (float)h0);
                        l[e + 4] = (_Float16)(v1 - (float)h1);
                    }
                    ah[tl][kk] = h; al[tl][kk] = l;
                }
            }
        }
        inpv = inp[t * NBATCH + b0 + col];
#pragma unroll
        for (int tl = 0; tl < 4; ++tl)
            bstv[tl] = *(const float4v*)(bst + t * NSTATE + 16 * tl + 4 * quad);
    };

    load_set(0, ah0, al0, bst0, inp0);
    load_set(1, ah1, al1, bst1, inp1);
    const float4v zero4 = {0.0f, 0.0f, 0.0f, 0.0f};

    auto step = [&](int t, int cur, half8 (&ah)[4][2], half8 (&al)[4][2],
                    float4v (&bstv)[4], float& inpv) {
        const int nxt = cur ^ 512;
        uint4v u_h0 = *(const uint4v*)(c_hi + cur + rd0);
        uint4v u_h1 = *(const uint4v*)(c_hi + cur + rd1);
        uint4v u_l0 = *(const uint4v*)(c_lo + cur + rd0);
        uint4v u_l1 = *(const uint4v*)(c_lo + cur + rd1);
        half8 ch[2] = { __builtin_bit_cast(half8, u_h0), __builtin_bit_cast(half8, u_h1) };
        half8 cl[2] = { __builtin_bit_cast(half8, u_l0), __builtin_bit_cast(half8, u_l1) };

        float4v acc[4];
#pragma unroll
        for (int tl = 0; tl < 4; ++tl) {
            float4v accA = bstv[tl] * inpv;
            accA = __builtin_amdgcn_mfma_f32_16x16x32_f16(ah[tl][0], ch[0], accA, 0, 0, 0);
            accA = __builtin_amdgcn_mfma_f32_16x16x32_f16(ah[tl][1], ch[1], accA, 0, 0, 0);
            float4v accB = __builtin_amdgcn_mfma_f32_16x16x32_f16(ah[tl][0], cl[0], zero4, 0, 0, 0);
            accB = __builtin_amdgcn_mfma_f32_16x16x32_f16(ah[tl][1], cl[1], accB, 0, 0, 0);
            accB = __builtin_amdgcn_mfma_f32_16x16x32_f16(al[tl][0], ch[0], accB, 0, 0, 0);
            accB = __builtin_amdgcn_mfma_f32_16x16x32_f16(al[tl][1], ch[1], accB, 0, 0, 0);
            acc[tl] = accA + accB;
        }

        float4v* outv = (float4v*)out;
#pragma unroll
        for (int tl = 0; tl < 4; ++tl)
            outv[(size_t)(t * NBATCH + b0 + col) * 16 + 4 * tl + quad] = acc[tl];

        int tp = t + 2; if (tp > L_SEQ - 1) tp = L_SEQ - 1;
        load_set(tp, ah, al, bstv, inpv);

#pragma unroll
        for (int tl = 0; tl < 4; ++tl) {
            float x = acc[tl].x, y = acc[tl].y, z = acc[tl].z, w = acc[tl].w;
            _Float16 hx = (_Float16)x, hy = (_Float16)y, hz = (_Float16)z, hw = (_Float16)w;
            half2s hp01; hp01.x = hx; hp01.y = hy;
            half2s hp23; hp23.x = hz; hp23.y = hw;
            half2s lp01; lp01.x = (_Float16)(x - (float)hx); lp01.y = (_Float16)(y - (float)hy);
            half2s lp23; lp23.x = (_Float16)(z - (float)hz); lp23.y = (_Float16)(w - (float)hw);
            uint2v hp = { __builtin_bit_cast(unsigned int, hp01), __builtin_bit_cast(unsigned int, hp23) };
            uint2v lp = { __builtin_bit_cast(unsigned int, lp01), __builtin_bit_cast(unsigned int, lp23) };
            *(uint2v*)(c_hi + nxt + wr[tl]) = hp;
            *(uint2v*)(c_lo + nxt + wr[tl]) = lp;
        }
    };

    for (int t = 0; t < L_SEQ; t += 2) {
        step(t,     0,   ah0, al0, bst0, inp0);
        step(t + 1, 512, ah1, al1, bst1, inp1);
    }
}

// ---------------------------------------------------------------------------
extern "C" void kernel_launch(void* const* d_in, const int* in_sizes, int n_in,
                              void* d_out, int out_size, void* d_ws, size_t ws_size,
                              hipStream_t stream) {
    const float* inputs = (const float*)d_in[0];
    const float* A_st   = (const float*)d_in[1];
    const float* B_st   = (const float*)d_in[2];
    float* out = (float*)d_out;

    const size_t n_a    = (size_t)L_SEQ * NSTATE * NSTATE;
    const size_t SZ_A   = n_a * sizeof(_Float16);                                 // 8 MB
    const size_t SZ_G   = (size_t)NCHK * TCHK * NSTATE * KDIM * sizeof(_Float16); // 16 MB
    const size_t SZ_S   = (size_t)NCHK * NBATCH * 32 * sizeof(unsigned int);      // 4 MB
    const size_t OFF_ALO = SZ_A;
    const size_t OFF_GHI = 2 * SZ_A;
    const size_t OFF_GLO = OFF_GHI + SZ_G;
    const size_t OFF_SHI = OFF_GLO + SZ_G;
    const size_t OFF_SLO = OFF_SHI + SZ_S;
    const size_t NEED    = OFF_SLO + SZ_S;                                        // 56 MB

    if (ws_size >= NEED) {
        char* ws = (char*)d_ws;
        _Float16* Ahi = (_Float16*)ws;
        _Float16* Alo = (_Float16*)(ws + OFF_ALO);
        _Float16* Ghi = (_Float16*)(ws + OFF_GHI);
        _Float16* Glo = (_Float16*)(ws + OFF_GLO);
        unsigned int* shi = (unsigned int*)(ws + OFF_SHI);
        unsigned int* slo = (unsigned int*)(ws + OFF_SLO);

        split_A_kernel<<<(int)(n_a / 256), 256, 0, stream>>>(A_st, Ahi, Alo);
        build_G_kernel<<<NCHK * 8, 64, 0, stream>>>(Ahi, Alo, B_st, Ghi, Glo);
        boundary2_kernel<<<NBATCH / 64, 256, 0, stream>>>(inputs, Ghi, Glo, shi, slo);
        apply2_kernel<<<NCHK * 8 * 16, 256, 0, stream>>>(inputs, Ghi, shi, slo, out);
    } else if (ws_size >= 2 * SZ_A) {
        _Float16* Ahi = (_Float16*)d_ws;
        _Float16* Alo = Ahi + n_a;
        split_A_kernel<<<(int)(n_a / 256), 256, 0, stream>>>(A_st, Ahi, Alo);
        hippo_scan_kernel<true><<<NBATCH / 16, 64, 0, stream>>>(inputs, B_st, A_st, Ahi, Alo, out);
    } else {
        hippo_scan_kernel<false><<<NBATCH / 16, 64, 0, stream>>>(inputs, B_st, A_st, nullptr, nullptr, out);
    }
}